// Round 1
// baseline (322.253 us; speedup 1.0000x reference)
//
#include <hip/hip_runtime.h>
#include <hip/hip_bf16.h>

typedef __hip_bfloat16 bf16;
typedef __attribute__((ext_vector_type(8))) short short8;
typedef __attribute__((ext_vector_type(4))) float f32x4;

#define MFMA(a, b, c) __builtin_amdgcn_mfma_f32_16x16x32_bf16((a), (b), (c), 0, 0, 0)

// ---------------------------------------------------------------------------
// Mask element-size detection: int32/f32 masks have every word in {0,1,1.0f};
// a random byte-bool mask cannot (p ~ (3/32)^256).
// flag = 0 -> 4-byte elements, flag = 1 -> 1-byte elements.
// ---------------------------------------------------------------------------
__global__ void detect_mask(const unsigned int* __restrict__ m, int* __restrict__ flag)
{
    __shared__ int bad;
    if (threadIdx.x == 0) bad = 0;
    __syncthreads();
    unsigned int w = m[threadIdx.x];   // first 1024 bytes, safe in both layouts
    bool ok = (w == 0u) || (w == 1u) || (w == 0x3F800000u);
    if (!ok) atomicAdd(&bad, 1);
    __syncthreads();
    if (threadIdx.x == 0) *flag = (bad == 0) ? 0 : 1;
}

// ---------------------------------------------------------------------------
// MLP folding: layer i computes y = x @ Wi^T + bi  (Wi is [128][128] row-major
// [out][in]).  Composed:  W_eff = W3*W2*W1,  b_eff = W3*(W2*b1 + b2) + b3.
// compose_a: T = W2*W1, bt = W2*b1 + b2      (f32 scratch)
// compose_b: W_eff = W3*T (bf16), b_eff = W3*bt + b3 (f32); Q head gets the
//            softmax scale rsqrt(128)*log2(e) folded in.
// ---------------------------------------------------------------------------
__global__ void compose_a(const float* __restrict__ qw, const float* __restrict__ qb,
                          const float* __restrict__ kw, const float* __restrict__ kb,
                          const float* __restrict__ vw, const float* __restrict__ vb,
                          float* __restrict__ T, float* __restrict__ bt)
{
    int h = blockIdx.x >> 7;
    int i = blockIdx.x & 127;
    int j = threadIdx.x;
    const float* W = (h == 0) ? qw : (h == 1) ? kw : vw;
    const float* bv = (h == 0) ? qb : (h == 1) ? kb : vb;
    const float* W1 = W;
    const float* W2 = W + 128 * 128;
    float acc = 0.f;
    for (int k = 0; k < 128; ++k) acc += W2[i * 128 + k] * W1[k * 128 + j];
    T[h * 16384 + i * 128 + j] = acc;
    if (j == 0) {
        float bacc = 0.f;
        for (int k = 0; k < 128; ++k) bacc += W2[i * 128 + k] * bv[k];
        bt[h * 128 + i] = bacc + bv[128 + i];
    }
}

__global__ void compose_b(const float* __restrict__ qw, const float* __restrict__ qb,
                          const float* __restrict__ kw, const float* __restrict__ kb,
                          const float* __restrict__ vw, const float* __restrict__ vb,
                          const float* __restrict__ T, const float* __restrict__ bt,
                          bf16* __restrict__ Weff, float* __restrict__ beff)
{
    int h = blockIdx.x >> 7;
    int i = blockIdx.x & 127;
    int j = threadIdx.x;
    const float* W = (h == 0) ? qw : (h == 1) ? kw : vw;
    const float* bv = (h == 0) ? qb : (h == 1) ? kb : vb;
    const float* W3 = W + 2 * 128 * 128;
    const float* Th = T + h * 16384;
    float acc = 0.f;
    for (int k = 0; k < 128; ++k) acc += W3[i * 128 + k] * Th[k * 128 + j];
    // Q head: fold 1/sqrt(128) and log2(e) (softmax done in exp2 domain)
    float scale = (h == 0) ? (1.4426950408889634f * rsqrtf(128.0f)) : 1.0f;
    Weff[h * 16384 + i * 128 + j] = __float2bfloat16(acc * scale);
    if (j == 0) {
        float bacc = 0.f;
        for (int k = 0; k < 128; ++k) bacc += W3[i * 128 + k] * bt[h * 128 + k];
        beff[h * 128 + i] = (bacc + bv[256 + i]) * scale;
    }
}

// ---------------------------------------------------------------------------
// Row-major projection:  Y[r][w] = sum_c X[r][c] * W[w][c] + bias[w]
// 64 rows/block, 4 waves, MFMA 16x16x32 bf16.  X staged bf16 in LDS with
// XOR-swizzle ((row&7)<<4 on byte offset) to kill ds_read_b128 bank conflicts.
// ---------------------------------------------------------------------------
__global__ __launch_bounds__(256) void proj_rm(
    const float* __restrict__ X, const bf16* __restrict__ Wb,
    const float* __restrict__ bias, bf16* __restrict__ Y)
{
    __shared__ alignas(16) char sX[64 * 256];   // 64 rows x 128 bf16
    int tid = threadIdx.x;
    int lane = tid & 63, wave = tid >> 6;
    int l16 = lane & 15, lhi = lane >> 4;
    long long r0 = (long long)blockIdx.x * 64;
    {
        int row = tid >> 2, seg = tid & 3;
        const float4* src = reinterpret_cast<const float4*>(X + (r0 + row) * 128 + seg * 32);
        int swz = (row & 7) << 4;
        char* dst0 = &sX[0] + row * 256;
#pragma unroll
        for (int i = 0; i < 8; ++i) {
            float4 v = src[i];
            bf16* d = (bf16*)(dst0 + ((seg * 64 + i * 8) ^ swz));
            d[0] = __float2bfloat16(v.x); d[1] = __float2bfloat16(v.y);
            d[2] = __float2bfloat16(v.z); d[3] = __float2bfloat16(v.w);
        }
    }
    __syncthreads();
    int rloc = wave * 16 + l16;
    int swzr = (rloc & 7) << 4;
    short8 a[4];
#pragma unroll
    for (int c4 = 0; c4 < 4; ++c4)
        a[c4] = *(const short8*)(&sX[0] + ((rloc * 256 + lhi * 16 + c4 * 64) ^ swzr));
    f32x4 acc[8] = {};
#pragma unroll
    for (int n = 0; n < 8; ++n) {
        const bf16* wr = Wb + (n * 16 + l16) * 128 + lhi * 8;
#pragma unroll
        for (int c4 = 0; c4 < 4; ++c4)
            acc[n] = MFMA(a[c4], *(const short8*)(wr + c4 * 32), acc[n]);
    }
#pragma unroll
    for (int n = 0; n < 8; ++n) {
        float bia = bias[l16 + 16 * n];
#pragma unroll
        for (int r = 0; r < 4; ++r) {
            long long q = r0 + wave * 16 + lhi * 4 + r;
            Y[q * 128 + l16 + 16 * n] = __float2bfloat16(acc[n][r] + bia);
        }
    }
}

// ---------------------------------------------------------------------------
// Transposed V projection:  Vt[b][w][m] = sum_c X2[b][m][c] * W[w][c] + bias[w]
// Computed directly transposed via A=W rows, B=x2 rows (both row-major frags).
// ---------------------------------------------------------------------------
__global__ __launch_bounds__(256) void proj_vt(
    const float* __restrict__ X2, const bf16* __restrict__ Wv,
    const float* __restrict__ bias, bf16* __restrict__ Vt, int M)
{
    __shared__ alignas(16) char sX[64 * 256];
    int tid = threadIdx.x;
    int lane = tid & 63, wave = tid >> 6;
    int l16 = lane & 15, lhi = lane >> 4;
    int mtiles = M >> 6;
    int b = blockIdx.x / mtiles, mt = blockIdx.x % mtiles;
    int m0 = mt * 64;
    {
        int row = tid >> 2, seg = tid & 3;
        const float4* src = reinterpret_cast<const float4*>(
            X2 + ((long long)b * M + m0 + row) * 128 + seg * 32);
        int swz = (row & 7) << 4;
        char* dst0 = &sX[0] + row * 256;
#pragma unroll
        for (int i = 0; i < 8; ++i) {
            float4 v = src[i];
            bf16* d = (bf16*)(dst0 + ((seg * 64 + i * 8) ^ swz));
            d[0] = __float2bfloat16(v.x); d[1] = __float2bfloat16(v.y);
            d[2] = __float2bfloat16(v.z); d[3] = __float2bfloat16(v.w);
        }
    }
    __syncthreads();
    int w0 = wave * 32;
    short8 a[2][4];
#pragma unroll
    for (int wt = 0; wt < 2; ++wt) {
        const bf16* wr = Wv + (w0 + wt * 16 + l16) * 128 + lhi * 8;
#pragma unroll
        for (int c4 = 0; c4 < 4; ++c4) a[wt][c4] = *(const short8*)(wr + c4 * 32);
    }
    f32x4 acc[2][4] = {};
#pragma unroll
    for (int mtl = 0; mtl < 4; ++mtl) {
        int rloc = mtl * 16 + l16;
        int swzr = (rloc & 7) << 4;
#pragma unroll
        for (int c4 = 0; c4 < 4; ++c4) {
            short8 xb = *(const short8*)(&sX[0] + ((rloc * 256 + lhi * 16 + c4 * 64) ^ swzr));
            acc[0][mtl] = MFMA(a[0][c4], xb, acc[0][mtl]);
            acc[1][mtl] = MFMA(a[1][c4], xb, acc[1][mtl]);
        }
    }
#pragma unroll
    for (int wt = 0; wt < 2; ++wt) {
#pragma unroll
        for (int r = 0; r < 4; ++r) {
            int w = w0 + wt * 16 + lhi * 4 + r;
            float bia = bias[w];
            bf16* dst = Vt + ((long long)b * 128 + w) * M + m0;
#pragma unroll
            for (int mtl = 0; mtl < 4; ++mtl)
                dst[mtl * 16 + l16] = __float2bfloat16(acc[wt][mtl][r] + bia);
        }
    }
}

// ---------------------------------------------------------------------------
// Fused masked attention + LayerNorm + residual.
// Q pre-scaled by rsqrt(128)*log2(e); softmax in exp2 domain.
// 4 waves/block, each wave owns 16 q rows; KV tile = 32; online softmax.
// Reference semantics: mask True -> excluded (-1e12 fill, then prob zeroed).
// ---------------------------------------------------------------------------
__global__ __launch_bounds__(256) void attn_kernel(
    const bf16* __restrict__ Q, const bf16* __restrict__ K, const bf16* __restrict__ Vt,
    const void* __restrict__ maskp, const int* __restrict__ flagp,
    const float* __restrict__ lng, const float* __restrict__ lnb,
    const float* __restrict__ x1, float* __restrict__ out,
    int B, int N, int M)
{
    __shared__ alignas(16) char Plds[4][1024];   // per-wave 16x32 bf16 P tile
    int nq = N >> 6;
    int nwg = gridDim.x;
    int bid = blockIdx.x;
    // XCD-bijective swizzle: 2 consecutive batches per XCD -> K/V stay in L2
    int wg = ((nwg & 7) == 0) ? ((bid & 7) * (nwg >> 3) + (bid >> 3)) : bid;
    int b = wg / nq, qt = wg % nq;
    int tid = threadIdx.x;
    int lane = tid & 63, wave = tid >> 6;
    int l16 = lane & 15, lhi = lane >> 4;
    int q0 = qt * 64 + wave * 16;
    int fl4 = (*flagp == 0);

    const bf16* qptr = Q + ((long long)b * N + q0 + l16) * 128 + lhi * 8;
    short8 aq[4];
#pragma unroll
    for (int c4 = 0; c4 < 4; ++c4) aq[c4] = *(const short8*)(qptr + c4 * 32);

    const bf16* Kbase = K + (long long)b * M * 128;
    const bf16* Vbase = Vt + (long long)b * 128 * M;
    long long mrow[4];
#pragma unroll
    for (int r = 0; r < 4; ++r)
        mrow[r] = ((long long)b * N + q0 + lhi * 4 + r) * (long long)M;

    f32x4 acc[8] = {};
    float mrun[4] = {-1e30f, -1e30f, -1e30f, -1e30f};
    float lrun[4] = {0.f, 0.f, 0.f, 0.f};

    for (int t0 = 0; t0 < M; t0 += 32) {
        // ---- mask (issued first, independent of MFMAs) ----
        unsigned int mk0[4], mk1[4];
        if (fl4) {
            const unsigned int* mp = (const unsigned int*)maskp;
#pragma unroll
            for (int r = 0; r < 4; ++r) {
                mk0[r] = mp[mrow[r] + t0 + l16];
                mk1[r] = mp[mrow[r] + t0 + 16 + l16];
            }
        } else {
            const unsigned char* mp = (const unsigned char*)maskp;
#pragma unroll
            for (int r = 0; r < 4; ++r) {
                mk0[r] = mp[mrow[r] + t0 + l16];
                mk1[r] = mp[mrow[r] + t0 + 16 + l16];
            }
        }
        // ---- S = Q K^T (exp2-domain logits) ----
        const bf16* kp0 = Kbase + (long long)(t0 + l16) * 128 + lhi * 8;
        const bf16* kp1 = kp0 + 16 * 128;
        f32x4 s0 = {0.f, 0.f, 0.f, 0.f}, s1 = {0.f, 0.f, 0.f, 0.f};
#pragma unroll
        for (int c4 = 0; c4 < 4; ++c4) {
            s0 = MFMA(aq[c4], *(const short8*)(kp0 + c4 * 32), s0);
            s1 = MFMA(aq[c4], *(const short8*)(kp1 + c4 * 32), s1);
        }
        // ---- online softmax (rows spread over 16-lane groups) ----
        float fac[4], p0[4], p1[4];
#pragma unroll
        for (int r = 0; r < 4; ++r) {
            float v0 = mk0[r] ? -1e30f : s0[r];
            float v1 = mk1[r] ? -1e30f : s1[r];
            float pm = fmaxf(v0, v1);
            pm = fmaxf(pm, __shfl_xor(pm, 1));
            pm = fmaxf(pm, __shfl_xor(pm, 2));
            pm = fmaxf(pm, __shfl_xor(pm, 4));
            pm = fmaxf(pm, __shfl_xor(pm, 8));
            float mnew = fmaxf(mrun[r], pm);
            fac[r] = exp2f(mrun[r] - mnew);
            p0[r] = mk0[r] ? 0.f : exp2f(s0[r] - mnew);
            p1[r] = mk1[r] ? 0.f : exp2f(s1[r] - mnew);
            float rs = p0[r] + p1[r];
            rs += __shfl_xor(rs, 1);
            rs += __shfl_xor(rs, 2);
            rs += __shfl_xor(rs, 4);
            rs += __shfl_xor(rs, 8);
            lrun[r] = lrun[r] * fac[r] + rs;
            mrun[r] = mnew;
        }
#pragma unroll
        for (int n = 0; n < 8; ++n) {
            acc[n][0] *= fac[0]; acc[n][1] *= fac[1];
            acc[n][2] *= fac[2]; acc[n][3] *= fac[3];
        }
        // ---- P (D-layout) -> LDS -> A-layout frag ----
        char* pb = &Plds[wave][0];
#pragma unroll
        for (int r = 0; r < 4; ++r) {
            int row = lhi * 4 + r;
            int swz = (row & 7) << 4;
            *(bf16*)(pb + ((row * 64 + l16 * 2) ^ swz)) = __float2bfloat16(p0[r]);
            *(bf16*)(pb + ((row * 64 + 32 + l16 * 2) ^ swz)) = __float2bfloat16(p1[r]);
        }
        short8 pa = *(const short8*)(pb + ((l16 * 64 + lhi * 16) ^ ((l16 & 7) << 4)));
        // ---- O += P V  (Vt rows are contiguous in m) ----
#pragma unroll
        for (int n = 0; n < 8; ++n) {
            const bf16* vp = Vbase + (long long)(n * 16 + l16) * M + t0 + lhi * 8;
            acc[n] = MFMA(pa, *(const short8*)vp, acc[n]);
        }
    }
    // ---- epilogue: normalize, LayerNorm, residual ----
    float inv[4];
#pragma unroll
    for (int r = 0; r < 4; ++r) inv[r] = (lrun[r] > 0.f) ? 1.f / lrun[r] : 0.f;
#pragma unroll
    for (int n = 0; n < 8; ++n) {
        acc[n][0] *= inv[0]; acc[n][1] *= inv[1];
        acc[n][2] *= inv[2]; acc[n][3] *= inv[3];
    }
    float mu[4], rstd[4];
#pragma unroll
    for (int r = 0; r < 4; ++r) {
        float su = 0.f;
#pragma unroll
        for (int n = 0; n < 8; ++n) su += acc[n][r];
        su += __shfl_xor(su, 1); su += __shfl_xor(su, 2);
        su += __shfl_xor(su, 4); su += __shfl_xor(su, 8);
        mu[r] = su * (1.f / 128.f);
        float sq = 0.f;
#pragma unroll
        for (int n = 0; n < 8; ++n) { float d = acc[n][r] - mu[r]; sq += d * d; }
        sq += __shfl_xor(sq, 1); sq += __shfl_xor(sq, 2);
        sq += __shfl_xor(sq, 4); sq += __shfl_xor(sq, 8);
        rstd[r] = rsqrtf(sq * (1.f / 128.f) + 1e-5f);
    }
#pragma unroll
    for (int n = 0; n < 8; ++n) {
        float g = lng[l16 + 16 * n], bb = lnb[l16 + 16 * n];
#pragma unroll
        for (int r = 0; r < 4; ++r) {
            long long idx = ((long long)b * N + q0 + lhi * 4 + r) * 128 + l16 + 16 * n;
            out[idx] = (acc[n][r] - mu[r]) * rstd[r] * g + bb + x1[idx];
        }
    }
}

// ---------------------------------------------------------------------------
extern "C" void kernel_launch(void* const* d_in, const int* in_sizes, int n_in,
                              void* d_out, int out_size, void* d_ws, size_t ws_size,
                              hipStream_t stream)
{
    const float* x1 = (const float*)d_in[0];
    const float* x2 = (const float*)d_in[1];
    const void* mask = d_in[2];
    const float* qw = (const float*)d_in[3];
    const float* qb = (const float*)d_in[4];
    const float* kw = (const float*)d_in[5];
    const float* kb = (const float*)d_in[6];
    const float* vw = (const float*)d_in[7];
    const float* vb = (const float*)d_in[8];
    const float* lng = (const float*)d_in[9];
    const float* lnb = (const float*)d_in[10];

    long long a = (long long)in_sizes[0] / 128;   // B*N
    long long c = (long long)in_sizes[1] / 128;   // B*M
    long long mm = (long long)in_sizes[2];        // B*N*M
    int B = (int)((a * c) / mm);
    int N = (int)(a / B);
    int M = (int)(c / B);

    char* p = (char*)d_ws;
    bf16* Q = (bf16*)p;    p += (size_t)a * 128 * sizeof(bf16);
    bf16* Kw = (bf16*)p;   p += (size_t)c * 128 * sizeof(bf16);
    bf16* Vt = (bf16*)p;   p += (size_t)c * 128 * sizeof(bf16);
    float* T = (float*)p;  p += 3 * 128 * 128 * sizeof(float);
    float* bt = (float*)p; p += 3 * 128 * sizeof(float);
    float* beff = (float*)p; p += 3 * 128 * sizeof(float);
    bf16* Weff = (bf16*)p; p += 3 * 128 * 128 * sizeof(bf16);
    int* flag = (int*)p;

    detect_mask<<<1, 256, 0, stream>>>((const unsigned int*)mask, flag);
    compose_a<<<384, 128, 0, stream>>>(qw, qb, kw, kb, vw, vb, T, bt);
    compose_b<<<384, 128, 0, stream>>>(qw, qb, kw, kb, vw, vb, T, bt, Weff, beff);

    proj_rm<<<(int)(a / 64), 256, 0, stream>>>(x1, Weff, beff, Q);
    proj_rm<<<(int)(c / 64), 256, 0, stream>>>(x2, Weff + 16384, beff + 128, Kw);
    proj_vt<<<(int)(c / 64), 256, 0, stream>>>(x2, Weff + 2 * 16384, beff + 256, Vt, M);

    attn_kernel<<<B * (N / 64), 256, 0, stream>>>(Q, Kw, Vt, mask, flag, lng, lnb,
                                                  x1, (float*)d_out, B, N, M);
}